// Round 1
// baseline (144.942 us; speedup 1.0000x reference)
//
#include <hip/hip_runtime.h>
#include <hip/hip_bf16.h>
#include <math.h>

#define EMB 1024
#define HEAD 64
#define NB 4
#define SEQ 4096
#define MTOT (NB * SEQ)

typedef __attribute__((ext_vector_type(8))) short bf16x8;
typedef __attribute__((ext_vector_type(4))) float f32x4;

static __device__ __forceinline__ unsigned short f2b(float f) {
    union { float f; unsigned u; } v; v.f = f;
    unsigned r = v.u + 0x7FFFu + ((v.u >> 16) & 1u);
    return (unsigned short)(r >> 16);
}

// ---------------------------------------------------------------------------
// Kernel 1: W transpose + bf16 cast.  Wt layout: [3][64 n][1024 k]
// ---------------------------------------------------------------------------
__global__ void wt_kernel(const float* __restrict__ Wq, const float* __restrict__ Wk,
                          const float* __restrict__ Wv, unsigned short* __restrict__ Wt) {
    const int idx = blockIdx.x * 256 + threadIdx.x;   // 3*64*1024 = 196608
    const int m = idx >> 16;
    const int r = idx & 65535;
    const int n = r >> 10, k = r & 1023;
    const float* W = (m == 0) ? Wq : (m == 1) ? Wk : Wv;
    Wt[idx] = f2b(W[k * HEAD + n]);
}

// ---------------------------------------------------------------------------
// Kernel 2: QKV projection. grid (MTOT/128, 3), 256 threads.
// C = x[128 x 1024] @ W[1024 x 64] (+bias), bf16 MFMA 16x16x32, BK=32.
// Q output pre-scaled by 1/sqrt(64).
// ---------------------------------------------------------------------------
__global__ __launch_bounds__(256) void proj_kernel(
    const float* __restrict__ x, const unsigned short* __restrict__ Wt3,
    const float* __restrict__ bq, const float* __restrict__ bk,
    const float* __restrict__ bv, unsigned short* __restrict__ qkv) {
    const int mat = blockIdx.y;
    const unsigned short* Wt = Wt3 + (size_t)mat * (HEAD * EMB);
    const float* bias = (mat == 0) ? bq : (mat == 1) ? bk : bv;
    unsigned short* out = qkv + (size_t)mat * MTOT * HEAD;
    const float osc = (mat == 0) ? 0.125f : 1.0f;

    __shared__ unsigned short Ax[128][40];   // +8 pad: 2-way conflicts only
    __shared__ unsigned short Wl[64][40];

    const int tid = threadIdx.x;
    const int wave = tid >> 6, lane = tid & 63;
    const int li = lane & 15, lg = lane >> 4;
    const int rbase = blockIdx.x * 128;

    f32x4 acc[2][4];
#pragma unroll
    for (int m = 0; m < 2; ++m)
#pragma unroll
        for (int n = 0; n < 4; ++n) acc[m][n] = (f32x4){0.f, 0.f, 0.f, 0.f};

    const int xr = tid >> 1, xc = (tid & 1) * 16;
    const int wr = tid >> 2, wc = (tid & 3) * 8;

    for (int k0 = 0; k0 < EMB; k0 += 32) {
        __syncthreads();
        // stage x tile [128][32] fp32 -> bf16 LDS
        const float* xs = x + (size_t)(rbase + xr) * EMB + k0 + xc;
        float xv[16];
#pragma unroll
        for (int i = 0; i < 16; i += 4) {
            const float4 t = *(const float4*)(xs + i);
            xv[i] = t.x; xv[i + 1] = t.y; xv[i + 2] = t.z; xv[i + 3] = t.w;
        }
        bf16x8 pa, pb;
#pragma unroll
        for (int i = 0; i < 8; ++i) {
            pa[i] = (short)f2b(xv[i]);
            pb[i] = (short)f2b(xv[8 + i]);
        }
        *(bf16x8*)&Ax[xr][xc] = pa;
        *(bf16x8*)&Ax[xr][xc + 8] = pb;
        // stage W^T tile [64 n][32 k]
        *(bf16x8*)&Wl[wr][wc] = *(const bf16x8*)(Wt + (size_t)wr * EMB + k0 + wc);
        __syncthreads();

        const bf16x8 a0 = *(const bf16x8*)&Ax[wave * 32 + li][lg * 8];
        const bf16x8 a1 = *(const bf16x8*)&Ax[wave * 32 + 16 + li][lg * 8];
#pragma unroll
        for (int n = 0; n < 4; ++n) {
            const bf16x8 b = *(const bf16x8*)&Wl[n * 16 + li][lg * 8];
            acc[0][n] = __builtin_amdgcn_mfma_f32_16x16x32_bf16(a0, b, acc[0][n], 0, 0, 0);
            acc[1][n] = __builtin_amdgcn_mfma_f32_16x16x32_bf16(a1, b, acc[1][n], 0, 0, 0);
        }
    }
    // epilogue: +bias, scale, cast, store. C layout: col=lane&15, row=(lane>>4)*4+reg
#pragma unroll
    for (int n = 0; n < 4; ++n) {
        const int col = n * 16 + li;
        const float bb = bias[col];
#pragma unroll
        for (int m = 0; m < 2; ++m)
#pragma unroll
            for (int r = 0; r < 4; ++r) {
                const int grow = rbase + wave * 32 + m * 16 + lg * 4 + r;
                out[(size_t)grow * HEAD + col] = f2b((acc[m][n][r] + bb) * osc);
            }
    }
}

// ---------------------------------------------------------------------------
// Kernel 3: flash attention (causal). grid (SEQ/64, NB), 256 threads.
// Each wave owns 16 q-rows; KV tiles of 64 staged in LDS (K XOR-swizzled,
// V transposed). Online softmax in fp32; P via per-wave LDS round-trip.
// ---------------------------------------------------------------------------
__global__ __launch_bounds__(256) void attn_kernel(
    const unsigned short* __restrict__ qkv, float* __restrict__ out) {
    const unsigned short* Qg = qkv;
    const unsigned short* Kg = qkv + (size_t)MTOT * HEAD;
    const unsigned short* Vg = qkv + (size_t)2 * MTOT * HEAD;

    const int qt = blockIdx.x, b = blockIdx.y;
    const int q0 = qt * 64;
    const int tid = threadIdx.x, wave = tid >> 6, lane = tid & 63;
    const int li = lane & 15, lg = lane >> 4;

    __shared__ unsigned short Kl[64 * 64];      // swizzled rows of 128B
    __shared__ unsigned short Vt[64][72];       // V^T, padded
    __shared__ unsigned short Pl[4][16][72];    // per-wave P tile

    const size_t base = (size_t)b * SEQ * HEAD;
    const int qrow = q0 + wave * 16 + li;
    const bf16x8 qf0 = *(const bf16x8*)(Qg + base + (size_t)qrow * HEAD + lg * 8);
    const bf16x8 qf1 = *(const bf16x8*)(Qg + base + (size_t)qrow * HEAD + 32 + lg * 8);

    f32x4 oa[4];
#pragma unroll
    for (int n = 0; n < 4; ++n) oa[n] = (f32x4){0.f, 0.f, 0.f, 0.f};
    float mS[4] = {-1e30f, -1e30f, -1e30f, -1e30f};
    float lS[4] = {0.f, 0.f, 0.f, 0.f};

    const int vr = tid >> 2, vc = (tid & 3) * 16;

    for (int t = 0; t <= qt; ++t) {
        const int kv0 = t * 64;
        __syncthreads();
        // ---- stage K tile, XOR-swizzled ----
#pragma unroll
        for (int i = 0; i < 2; ++i) {
            const int chunk = tid * 2 + i;          // 0..511
            const int r = chunk >> 3, c = (chunk & 7) * 8;
            const bf16x8 kvv = *(const bf16x8*)(Kg + base + (size_t)(kv0 + r) * HEAD + c);
            const int byte = (r * 128) | ((c * 2) ^ ((r & 7) << 4));
            *(bf16x8*)((char*)Kl + byte) = kvv;
        }
        // ---- stage V tile transposed ----
        {
            const unsigned short* vs = Vg + base + (size_t)(kv0 + vr) * HEAD + vc;
            const bf16x8 v0 = *(const bf16x8*)(vs);
            const bf16x8 v1 = *(const bf16x8*)(vs + 8);
#pragma unroll
            for (int i = 0; i < 8; ++i) {
                Vt[vc + i][vr] = (unsigned short)v0[i];
                Vt[vc + 8 + i][vr] = (unsigned short)v1[i];
            }
        }
        __syncthreads();

        // ---- S = Q K^T (pre-scaled) ----
        f32x4 s[4];
#pragma unroll
        for (int n = 0; n < 4; ++n) {
            const int brow = n * 16 + li;
            const int sw = (brow & 7) << 4;
            const bf16x8 b0 = *(const bf16x8*)((char*)Kl + ((brow * 128) | ((lg * 16) ^ sw)));
            const bf16x8 b1 = *(const bf16x8*)((char*)Kl + ((brow * 128) | ((64 + lg * 16) ^ sw)));
            f32x4 a = (f32x4){0.f, 0.f, 0.f, 0.f};
            a = __builtin_amdgcn_mfma_f32_16x16x32_bf16(qf0, b0, a, 0, 0, 0);
            a = __builtin_amdgcn_mfma_f32_16x16x32_bf16(qf1, b1, a, 0, 0, 0);
            s[n] = a;
        }
        // ---- causal mask on diagonal tile ----
        if (t == qt) {
#pragma unroll
            for (int n = 0; n < 4; ++n) {
                const int kv = kv0 + n * 16 + li;
#pragma unroll
                for (int r = 0; r < 4; ++r) {
                    const int q = q0 + wave * 16 + lg * 4 + r;
                    if (kv > q) s[n][r] = -1e30f;
                }
            }
        }
        // ---- online softmax (rows live in 16-lane groups) ----
        float cm[4];
#pragma unroll
        for (int r = 0; r < 4; ++r)
            cm[r] = fmaxf(fmaxf(s[0][r], s[1][r]), fmaxf(s[2][r], s[3][r]));
#pragma unroll
        for (int off = 1; off < 16; off <<= 1)
#pragma unroll
            for (int r = 0; r < 4; ++r)
                cm[r] = fmaxf(cm[r], __shfl_xor(cm[r], off));
        float sc[4];
#pragma unroll
        for (int r = 0; r < 4; ++r) {
            const float mn = fmaxf(mS[r], cm[r]);
            sc[r] = __expf(mS[r] - mn);
            mS[r] = mn;
        }
        float p[4][4], rs[4] = {0.f, 0.f, 0.f, 0.f};
#pragma unroll
        for (int n = 0; n < 4; ++n)
#pragma unroll
            for (int r = 0; r < 4; ++r) {
                p[n][r] = __expf(s[n][r] - mS[r]);
                rs[r] += p[n][r];
            }
#pragma unroll
        for (int off = 1; off < 16; off <<= 1)
#pragma unroll
            for (int r = 0; r < 4; ++r)
                rs[r] += __shfl_xor(rs[r], off);
#pragma unroll
        for (int r = 0; r < 4; ++r) lS[r] = lS[r] * sc[r] + rs[r];
#pragma unroll
        for (int n = 0; n < 4; ++n)
#pragma unroll
            for (int r = 0; r < 4; ++r) oa[n][r] *= sc[r];

        // ---- P -> per-wave LDS (bf16), reread as A-fragments ----
#pragma unroll
        for (int n = 0; n < 4; ++n)
#pragma unroll
            for (int r = 0; r < 4; ++r)
                Pl[wave][lg * 4 + r][n * 16 + li] = f2b(p[n][r]);

        const bf16x8 pf0 = *(const bf16x8*)&Pl[wave][li][lg * 8];
        const bf16x8 pf1 = *(const bf16x8*)&Pl[wave][li][32 + lg * 8];
#pragma unroll
        for (int n = 0; n < 4; ++n) {
            const bf16x8 vf0 = *(const bf16x8*)&Vt[n * 16 + li][lg * 8];
            const bf16x8 vf1 = *(const bf16x8*)&Vt[n * 16 + li][32 + lg * 8];
            oa[n] = __builtin_amdgcn_mfma_f32_16x16x32_bf16(pf0, vf0, oa[n], 0, 0, 0);
            oa[n] = __builtin_amdgcn_mfma_f32_16x16x32_bf16(pf1, vf1, oa[n], 0, 0, 0);
        }
    }

    // ---- epilogue: O = acc / l ----
    float* ob = out + ((size_t)b * SEQ + q0 + wave * 16) * HEAD;
#pragma unroll
    for (int n = 0; n < 4; ++n)
#pragma unroll
        for (int r = 0; r < 4; ++r)
            ob[(lg * 4 + r) * HEAD + n * 16 + li] = oa[n][r] / lS[r];
}

// ---------------------------------------------------------------------------
extern "C" void kernel_launch(void* const* d_in, const int* in_sizes, int n_in,
                              void* d_out, int out_size, void* d_ws, size_t ws_size,
                              hipStream_t stream) {
    const float* x  = (const float*)d_in[0];
    const float* Wq = (const float*)d_in[1];
    const float* bq = (const float*)d_in[2];
    const float* Wk = (const float*)d_in[3];
    const float* bk = (const float*)d_in[4];
    const float* Wv = (const float*)d_in[5];
    const float* bv = (const float*)d_in[6];

    unsigned short* Wt  = (unsigned short*)d_ws;        // 3*64*1024 bf16
    unsigned short* qkv = Wt + 3 * HEAD * EMB;          // 3*MTOT*HEAD bf16 (~6.3 MB)

    wt_kernel<<<dim3(768), dim3(256), 0, stream>>>(Wq, Wk, Wv, Wt);
    proj_kernel<<<dim3(MTOT / 128, 3), dim3(256), 0, stream>>>(x, Wt, bq, bk, bv, qkv);
    attn_kernel<<<dim3(SEQ / 64, NB), dim3(256), 0, stream>>>(qkv, (float*)d_out);
}

// Round 2
// 88.262 us; speedup vs baseline: 1.6422x; 1.6422x over previous
//
#include <hip/hip_runtime.h>
#include <hip/hip_bf16.h>
#include <math.h>

#define EMB 1024
#define HEAD 64
#define NB 4
#define SEQ 4096
#define MTOT (NB * SEQ)
// fold 1/sqrt(64) and log2(e) into Q so softmax runs in base-2 (v_exp_f32 native)
#define QSCALE (0.125f * 1.44269504088896f)

typedef __attribute__((ext_vector_type(8))) short bf16x8;
typedef __attribute__((ext_vector_type(4))) float f32x4;

static __device__ __forceinline__ unsigned short f2b(float f) {
    union { float f; unsigned u; } v; v.f = f;
    unsigned r = v.u + 0x7FFFu + ((v.u >> 16) & 1u);
    return (unsigned short)(r >> 16);
}
static __device__ __forceinline__ float b2f(unsigned short u) {
    union { unsigned u; float f; } v; v.u = ((unsigned)u) << 16; return v.f;
}

// ---------------------------------------------------------------------------
// Kernel 1: W transpose + bf16 cast.  Wt layout: [3][64 n][1024 k]
// ---------------------------------------------------------------------------
__global__ void wt_kernel(const float* __restrict__ Wq, const float* __restrict__ Wk,
                          const float* __restrict__ Wv, unsigned short* __restrict__ Wt) {
    const int idx = blockIdx.x * 256 + threadIdx.x;   // 3*64*1024 = 196608
    const int m = idx >> 16;
    const int r = idx & 65535;
    const int n = r >> 10, k = r & 1023;
    const float* W = (m == 0) ? Wq : (m == 1) ? Wk : Wv;
    Wt[idx] = f2b(W[k * HEAD + n]);
}

// ---------------------------------------------------------------------------
// Kernel 2: fused QKV projection (x read ONCE). grid MTOT/64, 256 threads.
// C = x[64 x 1024] @ W[1024 x 192] + bias.  N-frags 0-3: Q (pre-scaled),
// 4-7: K (row-major), 8-11: V written TRANSPOSED vt[b][h][s].
// ---------------------------------------------------------------------------
__global__ __launch_bounds__(256) void proj_kernel(
    const float* __restrict__ x, const unsigned short* __restrict__ Wt3,
    const float* __restrict__ bq, const float* __restrict__ bk,
    const float* __restrict__ bv, unsigned short* __restrict__ qg,
    unsigned short* __restrict__ kg, unsigned short* __restrict__ vt) {
    __shared__ unsigned short Ax[64][72];    // +8 pad
    __shared__ unsigned short Wl[192][72];

    const int tid = threadIdx.x;
    const int wave = tid >> 6, lane = tid & 63;
    const int li = lane & 15, lg = lane >> 4;
    const int rbase = blockIdx.x * 64;

    f32x4 acc[12];
#pragma unroll
    for (int n = 0; n < 12; ++n) acc[n] = (f32x4){0.f, 0.f, 0.f, 0.f};

    const int xr = tid >> 2, xc = (tid & 3) * 16;

    for (int k0 = 0; k0 < EMB; k0 += 64) {
        __syncthreads();
        // stage x tile [64][64] fp32 -> bf16
        const float* xp = x + (size_t)(rbase + xr) * EMB + k0 + xc;
        float xv[16];
#pragma unroll
        for (int i = 0; i < 16; i += 4) {
            const float4 t = *(const float4*)(xp + i);
            xv[i] = t.x; xv[i + 1] = t.y; xv[i + 2] = t.z; xv[i + 3] = t.w;
        }
        bf16x8 pa, pb;
#pragma unroll
        for (int i = 0; i < 8; ++i) { pa[i] = (short)f2b(xv[i]); pb[i] = (short)f2b(xv[8 + i]); }
        *(bf16x8*)&Ax[xr][xc] = pa;
        *(bf16x8*)&Ax[xr][xc + 8] = pb;
        // stage W tile [192][64]
#pragma unroll
        for (int i = 0; i < 6; ++i) {
            const int chunk = tid + 256 * i;
            const int row = chunk >> 3, c8 = (chunk & 7) * 8;
            *(bf16x8*)&Wl[row][c8] = *(const bf16x8*)(Wt3 + (size_t)row * EMB + k0 + c8);
        }
        __syncthreads();

        const bf16x8 a0 = *(const bf16x8*)&Ax[wave * 16 + li][lg * 8];
        const bf16x8 a1 = *(const bf16x8*)&Ax[wave * 16 + li][32 + lg * 8];
#pragma unroll
        for (int n = 0; n < 12; ++n) {
            const bf16x8 b0 = *(const bf16x8*)&Wl[n * 16 + li][lg * 8];
            const bf16x8 b1 = *(const bf16x8*)&Wl[n * 16 + li][32 + lg * 8];
            acc[n] = __builtin_amdgcn_mfma_f32_16x16x32_bf16(a0, b0, acc[n], 0, 0, 0);
            acc[n] = __builtin_amdgcn_mfma_f32_16x16x32_bf16(a1, b1, acc[n], 0, 0, 0);
        }
    }
    // epilogue
#pragma unroll
    for (int n = 0; n < 12; ++n) {
        const int mat = n >> 2;
        const int nc = (n & 3) * 16 + li;
        const float bb = (mat == 0) ? bq[nc] : (mat == 1) ? bk[nc] : bv[nc];
#pragma unroll
        for (int r = 0; r < 4; ++r) {
            const int grow = rbase + wave * 16 + lg * 4 + r;
            const float val = acc[n][r] + bb;
            if (mat == 0) {
                qg[(size_t)grow * HEAD + nc] = f2b(val * QSCALE);
            } else if (mat == 1) {
                kg[(size_t)grow * HEAD + nc] = f2b(val);
            } else {
                const int bi = grow >> 12, si = grow & 4095;
                vt[((size_t)bi * HEAD + nc) * SEQ + si] = f2b(val);
            }
        }
    }
}

// ---------------------------------------------------------------------------
// Kernel 3: flash attention, wave-independent, barrier-free main loop.
// grid (64, NB) x 512 threads = 8 waves: g = wave>>2 selects 32-row q-subtile
// (pairing bx / 127-bx for constant block work), kq = wave&3 is a 4-way
// strided KV split. KVBLK=64. K read direct from global (row-major = B-frag),
// V from pre-transposed vt. Partial (m,l,O) merged across kq via LDS at end.
// ---------------------------------------------------------------------------
__global__ __launch_bounds__(512, 2) void attn_kernel(
    const unsigned short* __restrict__ Qg, const unsigned short* __restrict__ Kg,
    const unsigned short* __restrict__ Vtg, float* __restrict__ out) {
    // per-wave 4608B region: P-transpose buffer [2][16][72] during the loop,
    // then reused as bf16 O-partial [32][72] for the merge (same size).
    __shared__ unsigned short U[8][2304];
    __shared__ float ml[8][32][2];

    const int tid = threadIdx.x, w = tid >> 6, lane = tid & 63;
    const int li = lane & 15, lg = lane >> 4;
    const int g = w >> 2, kq = w & 3;
    const int bx = blockIdx.x, b = blockIdx.y;
    const int qidx = g ? (127 - bx) : bx;          // qsub32 index, 0..127
    const int qa0 = qidx * 32;
    const size_t qb = (size_t)b * SEQ * HEAD;
    const unsigned short* vb = Vtg + (size_t)b * HEAD * SEQ;

    const bf16x8 qf00 = *(const bf16x8*)(Qg + qb + (size_t)(qa0 + li) * HEAD + lg * 8);
    const bf16x8 qf01 = *(const bf16x8*)(Qg + qb + (size_t)(qa0 + li) * HEAD + 32 + lg * 8);
    const bf16x8 qf10 = *(const bf16x8*)(Qg + qb + (size_t)(qa0 + 16 + li) * HEAD + lg * 8);
    const bf16x8 qf11 = *(const bf16x8*)(Qg + qb + (size_t)(qa0 + 16 + li) * HEAD + 32 + lg * 8);

    f32x4 oa[2][4];
    float mS[2][4], lS[2][4];
#pragma unroll
    for (int q = 0; q < 2; ++q)
#pragma unroll
        for (int n = 0; n < 4; ++n) oa[q][n] = (f32x4){0.f, 0.f, 0.f, 0.f};
#pragma unroll
    for (int q = 0; q < 2; ++q)
#pragma unroll
        for (int r = 0; r < 4; ++r) { mS[q][r] = -1e30f; lS[q][r] = 0.f; }

    unsigned short* Pw = U[w];
    const int ntiles = (qa0 + 95) >> 6;            // ceil((qa0+32)/64)

    for (int t = kq; t < ntiles; t += 4) {
        const int kv0 = t * 64;
        bf16x8 kf[4][2], vf[4][2];
#pragma unroll
        for (int n = 0; n < 4; ++n) {
            const unsigned short* kp = Kg + qb + (size_t)(kv0 + n * 16 + li) * HEAD + lg * 8;
            kf[n][0] = *(const bf16x8*)kp;
            kf[n][1] = *(const bf16x8*)(kp + 32);
            const unsigned short* vp = vb + (size_t)(n * 16 + li) * SEQ + kv0 + lg * 8;
            vf[n][0] = *(const bf16x8*)vp;
            vf[n][1] = *(const bf16x8*)(vp + 32);
        }
        // S = Q K^T  (two 16-row q streams share kf)
        f32x4 s[2][4];
#pragma unroll
        for (int n = 0; n < 4; ++n) {
            f32x4 z0 = (f32x4){0.f, 0.f, 0.f, 0.f};
            f32x4 z1 = (f32x4){0.f, 0.f, 0.f, 0.f};
            z0 = __builtin_amdgcn_mfma_f32_16x16x32_bf16(qf00, kf[n][0], z0, 0, 0, 0);
            s[0][n] = __builtin_amdgcn_mfma_f32_16x16x32_bf16(qf01, kf[n][1], z0, 0, 0, 0);
            z1 = __builtin_amdgcn_mfma_f32_16x16x32_bf16(qf10, kf[n][0], z1, 0, 0, 0);
            s[1][n] = __builtin_amdgcn_mfma_f32_16x16x32_bf16(qf11, kf[n][1], z1, 0, 0, 0);
        }
        // causal mask (diagonal region only)
        if (kv0 + 63 > qa0) {
#pragma unroll
            for (int n = 0; n < 4; ++n) {
                const int kv = kv0 + n * 16 + li;
#pragma unroll
                for (int q = 0; q < 2; ++q) {
                    const int qq = qa0 + q * 16 + lg * 4;
#pragma unroll
                    for (int r = 0; r < 4; ++r)
                        if (kv > qq + r) s[q][n][r] = -1e30f;
                }
            }
        }
        // online softmax (base-2), rows live across 16-lane groups
#pragma unroll
        for (int q = 0; q < 2; ++q) {
            float cm[4], sc[4], rs[4];
#pragma unroll
            for (int r = 0; r < 4; ++r)
                cm[r] = fmaxf(fmaxf(s[q][0][r], s[q][1][r]), fmaxf(s[q][2][r], s[q][3][r]));
#pragma unroll
            for (int off = 1; off < 16; off <<= 1)
#pragma unroll
                for (int r = 0; r < 4; ++r)
                    cm[r] = fmaxf(cm[r], __shfl_xor(cm[r], off));
#pragma unroll
            for (int r = 0; r < 4; ++r) {
                const float mn = fmaxf(mS[q][r], cm[r]);
                sc[r] = exp2f(mS[q][r] - mn);
                mS[q][r] = mn;
                rs[r] = 0.f;
            }
#pragma unroll
            for (int n = 0; n < 4; ++n)
#pragma unroll
                for (int r = 0; r < 4; ++r) {
                    const float p = exp2f(s[q][n][r] - mS[q][r]);
                    s[q][n][r] = p;
                    rs[r] += p;
                }
#pragma unroll
            for (int off = 1; off < 16; off <<= 1)
#pragma unroll
                for (int r = 0; r < 4; ++r)
                    rs[r] += __shfl_xor(rs[r], off);
#pragma unroll
            for (int r = 0; r < 4; ++r) lS[q][r] = lS[q][r] * sc[r] + rs[r];
#pragma unroll
            for (int n = 0; n < 4; ++n)
#pragma unroll
                for (int r = 0; r < 4; ++r) oa[q][n][r] *= sc[r];
            // P -> wave-local LDS (C-layout -> A-layout transpose)
#pragma unroll
            for (int n = 0; n < 4; ++n)
#pragma unroll
                for (int r = 0; r < 4; ++r)
                    Pw[q * 1152 + (lg * 4 + r) * 72 + n * 16 + li] = f2b(s[q][n][r]);
        }
        // PV
#pragma unroll
        for (int q = 0; q < 2; ++q) {
            const bf16x8 pf0 = *(const bf16x8*)&Pw[q * 1152 + li * 72 + lg * 8];
            const bf16x8 pf1 = *(const bf16x8*)&Pw[q * 1152 + li * 72 + 32 + lg * 8];
#pragma unroll
            for (int n = 0; n < 4; ++n) {
                oa[q][n] = __builtin_amdgcn_mfma_f32_16x16x32_bf16(pf0, vf[n][0], oa[q][n], 0, 0, 0);
                oa[q][n] = __builtin_amdgcn_mfma_f32_16x16x32_bf16(pf1, vf[n][1], oa[q][n], 0, 0, 0);
            }
        }
    }

    // publish partials: O (bf16, reuse Pw region) + (m,l)
#pragma unroll
    for (int q = 0; q < 2; ++q)
#pragma unroll
        for (int n = 0; n < 4; ++n)
#pragma unroll
            for (int r = 0; r < 4; ++r)
                Pw[(q * 16 + lg * 4 + r) * 72 + n * 16 + li] = f2b(oa[q][n][r]);
    if (li == 0) {
#pragma unroll
        for (int q = 0; q < 2; ++q)
#pragma unroll
            for (int r = 0; r < 4; ++r) {
                ml[w][q * 16 + lg * 4 + r][0] = mS[q][r];
                ml[w][q * 16 + lg * 4 + r][1] = lS[q][r];
            }
    }
    __syncthreads();

    // merge the 4 kq partials of this wave's own qsub; this wave owns 16 cols
#pragma unroll
    for (int q = 0; q < 2; ++q)
#pragma unroll
        for (int r = 0; r < 4; ++r) {
            const int row = q * 16 + lg * 4 + r;
            const float m0 = ml[g * 4 + 0][row][0], m1 = ml[g * 4 + 1][row][0];
            const float m2 = ml[g * 4 + 2][row][0], m3 = ml[g * 4 + 3][row][0];
            const float ms = fmaxf(fmaxf(m0, m1), fmaxf(m2, m3));
            const float c0 = exp2f(m0 - ms), c1 = exp2f(m1 - ms);
            const float c2 = exp2f(m2 - ms), c3 = exp2f(m3 - ms);
            const float ls = c0 * ml[g * 4 + 0][row][1] + c1 * ml[g * 4 + 1][row][1]
                           + c2 * ml[g * 4 + 2][row][1] + c3 * ml[g * 4 + 3][row][1];
            const int col = kq * 16 + li;
            const float o = c0 * b2f(U[g * 4 + 0][row * 72 + col])
                          + c1 * b2f(U[g * 4 + 1][row * 72 + col])
                          + c2 * b2f(U[g * 4 + 2][row * 72 + col])
                          + c3 * b2f(U[g * 4 + 3][row * 72 + col]);
            out[((size_t)b * SEQ + qa0 + row) * HEAD + col] = o / ls;
        }
}

// ---------------------------------------------------------------------------
extern "C" void kernel_launch(void* const* d_in, const int* in_sizes, int n_in,
                              void* d_out, int out_size, void* d_ws, size_t ws_size,
                              hipStream_t stream) {
    const float* x  = (const float*)d_in[0];
    const float* Wq = (const float*)d_in[1];
    const float* bq = (const float*)d_in[2];
    const float* Wk = (const float*)d_in[3];
    const float* bk = (const float*)d_in[4];
    const float* Wv = (const float*)d_in[5];
    const float* bv = (const float*)d_in[6];

    unsigned short* Wt = (unsigned short*)d_ws;          // 3*64*1024
    unsigned short* qg = Wt + 3 * HEAD * EMB;            // MTOT*64 bf16 (Q, pre-scaled)
    unsigned short* kg = qg + (size_t)MTOT * HEAD;       // MTOT*64 bf16 (K)
    unsigned short* vt = kg + (size_t)MTOT * HEAD;       // [NB][HEAD][SEQ] bf16 (V^T)

    wt_kernel<<<dim3(768), dim3(256), 0, stream>>>(Wq, Wk, Wv, Wt);
    proj_kernel<<<dim3(MTOT / 64), dim3(256), 0, stream>>>(x, Wt, bq, bk, bv, qg, kg, vt);
    attn_kernel<<<dim3(64, NB), dim3(512), 0, stream>>>(qg, kg, vt, (float*)d_out);
}